// Round 9
// baseline (203.665 us; speedup 1.0000x reference)
//
#include <hip/hip_runtime.h>
#include <hip/hip_fp16.h>

#define N_FEAT 128
#define HID 16
#define NPB 128          // nodes per fine bucket (7-bit local dst)
#define NPC 512          // nodes per coarse bucket (= 4 fine)
#define KMAX 1024        // max fine buckets (K = 782 here)
#define KCMAX 256        // max coarse buckets (KC = 196 here)
#define SEGCAP 8192      // max edges per fine bucket in sort LDS
#define EPT 16           // edges per thread in bin1
#define BATCH 16         // parallel gathers per batch in agg kernels

// ctrl (ints): bcnt@0(1024) | bstart@1024(1056) | gcursorF@2080(1024) | gcursorC@3104(256)
#define CTRL_INTS 3584

static __device__ __forceinline__ int ph2(float a, float b) {
    __half2 h = __floats2half2_rn(a, b);
    return *reinterpret_cast<int*>(&h);
}

// ================= fine histogram (dst>>7) ================================
__global__ void bhist_kernel(const int* __restrict__ dst,
                             int* __restrict__ bcnt, int E, int K) {
    __shared__ int h[KMAX];
    for (int i = threadIdx.x; i < KMAX; i += 256) h[i] = 0;
    __syncthreads();
    for (long long e = (long long)blockIdx.x * 256 + threadIdx.x; e < E;
         e += (long long)gridDim.x * 256)
        atomicAdd(&h[dst[e] >> 7], 1);
    __syncthreads();
    for (int i = threadIdx.x; i < K; i += 256)
        if (h[i]) atomicAdd(&bcnt[i], h[i]);
}

// ================= scan of fine counts; fine + coarse cursors =============
__global__ void bscan_kernel(const int* __restrict__ bcnt,
                             int* __restrict__ bstart,
                             int* __restrict__ gcursorF,
                             int* __restrict__ gcursorC, int K, int E) {
    __shared__ int l[KMAX];
    int t = threadIdx.x;
    int v = (t < K) ? bcnt[t] : 0;
    l[t] = v;
    __syncthreads();
    for (int off = 1; off < KMAX; off <<= 1) {
        int tmp = (t >= off) ? l[t - off] : 0;
        __syncthreads();
        l[t] += tmp;
        __syncthreads();
    }
    int excl = l[t] - v;
    bstart[t]   = excl;          // == E for t >= K
    gcursorF[t] = excl;
    if ((t & 3) == 0) gcursorC[t >> 2] = excl;   // coarse start = fine[4c]
    if (t == 0) bstart[KMAX] = E;
}

// ===== bin1: partition edges into 196 coarse buckets (register-staged) ====
__global__ void bin1_kernel(const int* __restrict__ src,
                            const int* __restrict__ dst,
                            int* __restrict__ gcursorC,
                            int* __restrict__ binnedA, int E) {
    __shared__ int rcnt[KCMAX];
    __shared__ int rbase[KCMAX];
    int base = blockIdx.x * (256 * EPT);
    if (base >= E) return;

    if (threadIdx.x < KCMAX) rcnt[threadIdx.x] = 0;
    __syncthreads();

    int myb[EPT], myoff[EPT], mypack[EPT];
#pragma unroll
    for (int q = 0; q < EPT; ++q) {
        int e = base + q * 256 + threadIdx.x;
        myb[q] = -1;
        if (e < E) {
            int d = dst[e], s = src[e];
            int b = d >> 9;                        // coarse bucket
            myb[q]    = b;
            mypack[q] = ((d & 511) << 17) | s;     // 9-bit local | 17-bit src
            myoff[q]  = atomicAdd(&rcnt[b], 1);
        }
    }
    __syncthreads();
    if (threadIdx.x < KCMAX) {
        int c = rcnt[threadIdx.x];
        if (c > 0) rbase[threadIdx.x] = atomicAdd(&gcursorC[threadIdx.x], c);
    }
    __syncthreads();
#pragma unroll
    for (int q = 0; q < EPT; ++q)
        if (myb[q] >= 0) binnedA[rbase[myb[q]] + myoff[q]] = mypack[q];
}

// ===== bin2: split one quarter of one coarse bucket into its 4 fine =======
// wave-ballot ranked write: one global atomic per (wave, iter, fine)
__global__ void bin2_kernel(const int* __restrict__ binnedA,
                            const int* __restrict__ bstart,
                            int* __restrict__ gcursorF,
                            int* __restrict__ binned) {
    int c = blockIdx.x >> 2, q = blockIdx.x & 3;
    int s = bstart[c << 2];
    int t = bstart[(c + 1) << 2];
    int len = t - s;
    int qs = s + (int)(((long long)len * q) >> 2);
    int qe = s + (int)(((long long)len * (q + 1)) >> 2);
    int lane = threadIdx.x & 63;
    unsigned long long ltmask = (1ULL << lane) - 1;

    for (int k0 = qs + (threadIdx.x & ~63); k0 < qe; k0 += 256) {
        int e = k0 + lane;
        bool valid = e < qe;
        int p = valid ? binnedA[e] : 0;
        int dl9 = p >> 17;
        int f = dl9 >> 7;                          // 0..3 fine within coarse
        unsigned long long vm = __ballot(valid);
        unsigned long long b0 = __ballot(valid && (f & 1));
        unsigned long long b1 = __ballot(valid && (f & 2));
        unsigned long long m = ((f & 1) ? b0 : ~b0) & ((f & 2) ? b1 : ~b1) & vm;
        int pre = __popcll(m & ltmask);
        int tot = __popcll(m);
        int leader = m ? (__ffsll((unsigned long long)m) - 1) : 0;
        int base = 0;
        if (valid && lane == leader)
            base = atomicAdd(&gcursorF[(c << 2) + f], tot);
        base = __shfl(base, leader, 64);
        if (valid)
            binned[base + pre] = ((dl9 & 127) << 17) | (p & 0x1FFFF);
    }
}

// ===== per-fine-bucket counting sort (in place) + row_start + dinv ========
__global__ void sort_kernel(const int* __restrict__ bstart,
                            int* __restrict__ binned,
                            int* __restrict__ row_start,
                            float* __restrict__ dinv, int n, int E) {
    __shared__ int seg[SEGCAP];
    __shared__ int cnt[NPB];
    __shared__ int excl[NPB];
    __shared__ int cur[NPB];
    int b = blockIdx.x;
    int rs = bstart[b], re = bstart[b + 1];
    int m = re - rs;
    if (m > SEGCAP) m = SEGCAP;
    int t = threadIdx.x;

    if (t < NPB) cnt[t] = 0;
    __syncthreads();

    for (int k = t; k < m; k += 256) {
        int p = binned[rs + k];
        seg[k] = p;
        atomicAdd(&cnt[p >> 17], 1);
    }
    __syncthreads();

    if (t < NPB) excl[t] = cnt[t];
    __syncthreads();
    for (int off = 1; off < NPB; off <<= 1) {
        int v = (t < NPB && t >= off) ? excl[t - off] : 0;
        __syncthreads();
        if (t < NPB) excl[t] += v;
        __syncthreads();
    }

    int vbase = b * NPB;
    if (t < NPB) {
        int e0 = excl[t] - cnt[t];
        cur[t] = e0;
        int v = vbase + t;
        if (v < n) {
            row_start[v] = rs + e0;
            dinv[v] = rsqrtf((float)cnt[t] + 1.0f);
        }
    }
    if (b == 0 && t == 0) row_start[n] = E;
    __syncthreads();

    for (int k = t; k < m; k += 256) {
        int p = seg[k];
        int pos = rs + atomicAdd(&cur[p >> 17], 1);
        binned[pos] = p & 0x1FFFF;                 // sorted src
    }
}

// ========= xform1: g1h[v,:] = fp16((x[v,:] @ W1) * dinv[v]) ===============
__global__ void xform1_kernel(const float* __restrict__ x,
                              const float* __restrict__ W1,
                              const float* __restrict__ dinv,
                              int4* __restrict__ g1h, int n) {
    __shared__ float Ws[N_FEAT * HID];
    for (int i = threadIdx.x; i < N_FEAT * HID; i += blockDim.x)
        Ws[i] = W1[i];
    __syncthreads();

    int v = blockIdx.x * blockDim.x + threadIdx.x;
    if (v >= n) return;

    float acc[HID];
#pragma unroll
    for (int j = 0; j < HID; ++j) acc[j] = 0.0f;

    const float4* xr = (const float4*)(x + (size_t)v * N_FEAT);
#pragma unroll
    for (int k4 = 0; k4 < N_FEAT / 4; ++k4) {
        float4 xv = xr[k4];
        int k = k4 * 4;
#pragma unroll
        for (int j = 0; j < HID; ++j) {
            acc[j] += xv.x * Ws[(k + 0) * HID + j]
                    + xv.y * Ws[(k + 1) * HID + j]
                    + xv.z * Ws[(k + 2) * HID + j]
                    + xv.w * Ws[(k + 3) * HID + j];
        }
    }
    float dv = dinv[v];
    int4 w0, w1;
    w0.x = ph2(acc[0] * dv,  acc[1] * dv);
    w0.y = ph2(acc[2] * dv,  acc[3] * dv);
    w0.z = ph2(acc[4] * dv,  acc[5] * dv);
    w0.w = ph2(acc[6] * dv,  acc[7] * dv);
    w1.x = ph2(acc[8] * dv,  acc[9] * dv);
    w1.y = ph2(acc[10] * dv, acc[11] * dv);
    w1.z = ph2(acc[12] * dv, acc[13] * dv);
    w1.w = ph2(acc[14] * dv, acc[15] * dv);
    g1h[(size_t)v * 2 + 0] = w0;
    g1h[(size_t)v * 2 + 1] = w1;
}

// ===== layer-1 aggregation: fp16 gathers, 2 lanes/node, 16-deep batches ===
__global__ __launch_bounds__(256) void agg_raw_kernel(
        const int* __restrict__ row_start,
        const int* __restrict__ slots,
        const int4* __restrict__ g,        // 2 int4 (16 fp16) per node
        float4* __restrict__ a, int n) {   // 4 float4 per node
    int v = blockIdx.x * 128 + (threadIdx.x >> 1);
    int h = threadIdx.x & 1;
    if (v >= n) return;

    int rs = row_start[v], re = row_start[v + 1];
    float acc[8];
#pragma unroll
    for (int j = 0; j < 8; ++j) acc[j] = 0.0f;

    for (int k = rs; k < re; k += BATCH) {
        int e[BATCH];
#pragma unroll
        for (int u = 0; u < BATCH; ++u)
            e[u] = slots[min(k + u, re - 1)];
        int4 t[BATCH];
#pragma unroll
        for (int u = 0; u < BATCH; ++u)
            t[u] = g[(size_t)e[u] * 2 + h];
#pragma unroll
        for (int u = 0; u < BATCH; ++u) {
            if (k + u < re) {
                const __half2* hp = (const __half2*)&t[u];
                float2 f0 = __half22float2(hp[0]);
                float2 f1 = __half22float2(hp[1]);
                float2 f2 = __half22float2(hp[2]);
                float2 f3 = __half22float2(hp[3]);
                acc[0] += f0.x; acc[1] += f0.y;
                acc[2] += f1.x; acc[3] += f1.y;
                acc[4] += f2.x; acc[5] += f2.y;
                acc[6] += f3.x; acc[7] += f3.y;
            }
        }
    }
    float4 r0 = {acc[0], acc[1], acc[2], acc[3]};
    float4 r1 = {acc[4], acc[5], acc[6], acc[7]};
    a[(size_t)v * 4 + h * 2 + 0] = r0;
    a[(size_t)v * 4 + h * 2 + 1] = r1;
}

// == fin1: t=relu(dv*(a+g1self)+b1); g2h = fp16(dv*(t@W2)) =================
__global__ void fin1_kernel(const float* __restrict__ a,
                            const int4* __restrict__ g1h,
                            const float* __restrict__ dinv,
                            const float* __restrict__ b1,
                            const float* __restrict__ W2,
                            int4* __restrict__ g2h, int n) {
    __shared__ float W2s[HID * HID];
    W2s[threadIdx.x] = W2[threadIdx.x];   // blockDim == 256
    __syncthreads();

    int v = blockIdx.x * 256 + threadIdx.x;
    if (v >= n) return;
    float dv = dinv[v];

    int4 s0 = g1h[(size_t)v * 2 + 0];
    int4 s1 = g1h[(size_t)v * 2 + 1];
    const __half2* hp0 = (const __half2*)&s0;
    const __half2* hp1 = (const __half2*)&s1;
    float self[HID];
#pragma unroll
    for (int q = 0; q < 4; ++q) {
        float2 f = __half22float2(hp0[q]);
        self[q * 2] = f.x; self[q * 2 + 1] = f.y;
    }
#pragma unroll
    for (int q = 0; q < 4; ++q) {
        float2 f = __half22float2(hp1[q]);
        self[8 + q * 2] = f.x; self[8 + q * 2 + 1] = f.y;
    }

    const float4* a4 = (const float4*)(a + (size_t)v * HID);
    float t[HID];
#pragma unroll
    for (int q = 0; q < 4; ++q) {
        float4 av = a4[q];
        t[q * 4 + 0] = fmaxf(dv * (av.x + self[q * 4 + 0]) + b1[q * 4 + 0], 0.0f);
        t[q * 4 + 1] = fmaxf(dv * (av.y + self[q * 4 + 1]) + b1[q * 4 + 1], 0.0f);
        t[q * 4 + 2] = fmaxf(dv * (av.z + self[q * 4 + 2]) + b1[q * 4 + 2], 0.0f);
        t[q * 4 + 3] = fmaxf(dv * (av.w + self[q * 4 + 3]) + b1[q * 4 + 3], 0.0f);
    }

    float hh[HID];
#pragma unroll
    for (int j2 = 0; j2 < HID; ++j2) {
        float s = 0.0f;
#pragma unroll
        for (int j = 0; j < HID; ++j) s += t[j] * W2s[j * HID + j2];
        hh[j2] = s * dv;
    }
    int4 w0, w1;
    w0.x = ph2(hh[0], hh[1]);   w0.y = ph2(hh[2], hh[3]);
    w0.z = ph2(hh[4], hh[5]);   w0.w = ph2(hh[6], hh[7]);
    w1.x = ph2(hh[8], hh[9]);   w1.y = ph2(hh[10], hh[11]);
    w1.z = ph2(hh[12], hh[13]); w1.w = ph2(hh[14], hh[15]);
    g2h[(size_t)v * 2 + 0] = w0;
    g2h[(size_t)v * 2 + 1] = w1;
}

// ===== layer-2 aggregation + finalize + bias (fp16 gathers) ===============
__global__ __launch_bounds__(256) void agg_fin_kernel(
        const int* __restrict__ row_start,
        const int* __restrict__ slots,
        const int4* __restrict__ g,        // g2h
        const float* __restrict__ dinv,
        const float* __restrict__ b2,
        float4* __restrict__ out, int n) {
    int v = blockIdx.x * 128 + (threadIdx.x >> 1);
    int h = threadIdx.x & 1;
    if (v >= n) return;

    int rs = row_start[v], re = row_start[v + 1];
    float acc[8];
#pragma unroll
    for (int j = 0; j < 8; ++j) acc[j] = 0.0f;

    for (int k = rs; k < re; k += BATCH) {
        int e[BATCH];
#pragma unroll
        for (int u = 0; u < BATCH; ++u)
            e[u] = slots[min(k + u, re - 1)];
        int4 t[BATCH];
#pragma unroll
        for (int u = 0; u < BATCH; ++u)
            t[u] = g[(size_t)e[u] * 2 + h];
#pragma unroll
        for (int u = 0; u < BATCH; ++u) {
            if (k + u < re) {
                const __half2* hp = (const __half2*)&t[u];
                float2 f0 = __half22float2(hp[0]);
                float2 f1 = __half22float2(hp[1]);
                float2 f2 = __half22float2(hp[2]);
                float2 f3 = __half22float2(hp[3]);
                acc[0] += f0.x; acc[1] += f0.y;
                acc[2] += f1.x; acc[3] += f1.y;
                acc[4] += f2.x; acc[5] += f2.y;
                acc[6] += f3.x; acc[7] += f3.y;
            }
        }
    }

    float dv = dinv[v];
    int4 sq = g[(size_t)v * 2 + h];
    const __half2* hp = (const __half2*)&sq;
    float2 f0 = __half22float2(hp[0]);
    float2 f1 = __half22float2(hp[1]);
    float2 f2 = __half22float2(hp[2]);
    float2 f3 = __half22float2(hp[3]);
    const float4* b24 = (const float4*)b2;
    float4 bb0 = b24[h * 2 + 0], bb1 = b24[h * 2 + 1];
    float4 o0, o1;
    o0.x = dv * (acc[0] + f0.x) + bb0.x;
    o0.y = dv * (acc[1] + f0.y) + bb0.y;
    o0.z = dv * (acc[2] + f1.x) + bb0.z;
    o0.w = dv * (acc[3] + f1.y) + bb0.w;
    o1.x = dv * (acc[4] + f2.x) + bb1.x;
    o1.y = dv * (acc[5] + f2.y) + bb1.y;
    o1.z = dv * (acc[6] + f3.x) + bb1.z;
    o1.w = dv * (acc[7] + f3.y) + bb1.w;
    out[(size_t)v * 4 + h * 2 + 0] = o0;
    out[(size_t)v * 4 + h * 2 + 1] = o1;
}

// ========================= fallback (atomic, fp32) path ====================
__global__ void deg_kernel(const int* __restrict__ dst,
                           float* __restrict__ deg, int E) {
    int e = blockIdx.x * blockDim.x + threadIdx.x;
    if (e < E) atomicAdd(&deg[dst[e]], 1.0f);
}

__global__ void dinv_kernel(float* __restrict__ deg, int n) {
    int v = blockIdx.x * blockDim.x + threadIdx.x;
    if (v < n) deg[v] = rsqrtf(deg[v] + 1.0f);
}

__global__ void agg_kernel(const int* __restrict__ src,
                           const int* __restrict__ dst,
                           const float* __restrict__ g,
                           float* __restrict__ acc, long long total) {
    long long i = (long long)blockIdx.x * blockDim.x + threadIdx.x;
    if (i >= total) return;
    int e = (int)(i >> 4);
    int j = (int)(i & 15);
    atomicAdd(&acc[(size_t)dst[e] * HID + j], g[(size_t)src[e] * HID + j]);
}

__global__ void xform1_flat_kernel(const float* __restrict__ x,
                                   const float* __restrict__ W1,
                                   const float* __restrict__ dinv,
                                   float* __restrict__ g1, int n) {
    __shared__ float Ws[N_FEAT * HID];
    for (int i = threadIdx.x; i < N_FEAT * HID; i += blockDim.x)
        Ws[i] = W1[i];
    __syncthreads();
    int v = blockIdx.x * blockDim.x + threadIdx.x;
    if (v >= n) return;
    float acc[HID];
#pragma unroll
    for (int j = 0; j < HID; ++j) acc[j] = 0.0f;
    const float4* xr = (const float4*)(x + (size_t)v * N_FEAT);
#pragma unroll
    for (int k4 = 0; k4 < N_FEAT / 4; ++k4) {
        float4 xv = xr[k4];
        int k = k4 * 4;
#pragma unroll
        for (int j = 0; j < HID; ++j) {
            acc[j] += xv.x * Ws[(k + 0) * HID + j]
                    + xv.y * Ws[(k + 1) * HID + j]
                    + xv.z * Ws[(k + 2) * HID + j]
                    + xv.w * Ws[(k + 3) * HID + j];
        }
    }
    float dv = dinv[v];
    float4* outp = (float4*)(g1 + (size_t)v * HID);
#pragma unroll
    for (int q = 0; q < HID / 4; ++q) {
        float4 o;
        o.x = acc[q * 4 + 0] * dv;
        o.y = acc[q * 4 + 1] * dv;
        o.z = acc[q * 4 + 2] * dv;
        o.w = acc[q * 4 + 3] * dv;
        outp[q] = o;
    }
}

__global__ void fin1_xform2_nolds_kernel(float* __restrict__ a1,
                                         const float* __restrict__ g1,
                                         const float* __restrict__ dinv,
                                         const float* __restrict__ b1,
                                         const float* __restrict__ W2,
                                         int n) {
    int v = blockIdx.x * blockDim.x + threadIdx.x;
    if (v >= n) return;
    float dv = dinv[v];
    const float4* a4 = (const float4*)(a1 + (size_t)v * HID);
    const float4* s4 = (const float4*)(g1 + (size_t)v * HID);
    float t[HID];
#pragma unroll
    for (int q = 0; q < HID / 4; ++q) {
        float4 av = a4[q];
        float4 sv = s4[q];
        t[q * 4 + 0] = fmaxf(dv * (av.x + sv.x) + b1[q * 4 + 0], 0.0f);
        t[q * 4 + 1] = fmaxf(dv * (av.y + sv.y) + b1[q * 4 + 1], 0.0f);
        t[q * 4 + 2] = fmaxf(dv * (av.z + sv.z) + b1[q * 4 + 2], 0.0f);
        t[q * 4 + 3] = fmaxf(dv * (av.w + sv.w) + b1[q * 4 + 3], 0.0f);
    }
    float4* outp = (float4*)(a1 + (size_t)v * HID);
#pragma unroll
    for (int q = 0; q < HID / 4; ++q) {
        float4 o;
        float h[4];
#pragma unroll
        for (int r = 0; r < 4; ++r) {
            int j2 = q * 4 + r;
            float acc = 0.0f;
#pragma unroll
            for (int j = 0; j < HID; ++j) acc += t[j] * W2[j * HID + j2];
            h[r] = acc * dv;
        }
        o.x = h[0]; o.y = h[1]; o.z = h[2]; o.w = h[3];
        outp[q] = o;
    }
}

__global__ void fin2_kernel(float* __restrict__ out,
                            const float* __restrict__ g2,
                            const float* __restrict__ dinv,
                            const float* __restrict__ b2, int n) {
    int v = blockIdx.x * blockDim.x + threadIdx.x;
    if (v >= n) return;
    float dv = dinv[v];
    float4* o4 = (float4*)(out + (size_t)v * HID);
    const float4* g4 = (const float4*)(g2 + (size_t)v * HID);
#pragma unroll
    for (int q = 0; q < HID / 4; ++q) {
        float4 ov = o4[q];
        float4 gv = g4[q];
        float4 r;
        r.x = dv * (ov.x + gv.x) + b2[q * 4 + 0];
        r.y = dv * (ov.y + gv.y) + b2[q * 4 + 1];
        r.z = dv * (ov.z + gv.z) + b2[q * 4 + 2];
        r.w = dv * (ov.w + gv.w) + b2[q * 4 + 3];
        o4[q] = r;
    }
}

// ===========================================================================
extern "C" void kernel_launch(void* const* d_in, const int* in_sizes, int n_in,
                              void* d_out, int out_size, void* d_ws, size_t ws_size,
                              hipStream_t stream) {
    const float* x  = (const float*)d_in[0];
    const int*   ei = (const int*)d_in[1];     // int32 (JAX x64 disabled)
    const float* W1 = (const float*)d_in[2];
    const float* b1 = (const float*)d_in[3];
    const float* W2 = (const float*)d_in[4];
    const float* b2 = (const float*)d_in[5];
    float* out = (float*)d_out;

    const int n = in_sizes[0] / N_FEAT;         // 100000
    const int E = in_sizes[1] / 2;              // 3200000
    const int* src = ei;
    const int* dst = ei + E;

    const int B = 256;
    size_t nal = ((size_t)n + 255) & ~(size_t)255;
    const int K  = (n + NPB - 1) / NPB;         // 782 fine buckets
    const int KC = (K + 3) / 4;                 // 196 coarse buckets

    // ws: binned(E) | ctrl | row_start(nal+64) | dinv(nal) |
    //     g1h(8nal) | g2h(8nal) | a(16nal)      [binnedA aliases g1h..a]
    size_t need = ((size_t)E + CTRL_INTS + 34 * nal + 64) * sizeof(int);

    if (ws_size >= need && K <= KMAX && KC <= KCMAX && 32 * nal >= (size_t)E) {
        int*   binned    = (int*)d_ws;                   // E
        int*   ctrl      = binned + E;                   // CTRL_INTS
        int*   bcnt      = ctrl;                         // 1024
        int*   bstart    = ctrl + 1024;                  // 1056
        int*   gcursorF  = ctrl + 2080;                  // 1024
        int*   gcursorC  = ctrl + 3104;                  // 256
        int*   row_start = ctrl + CTRL_INTS;             // nal + 64
        float* dinv      = (float*)(row_start + nal + 64);
        int4*  g1h       = (int4*)(dinv + nal);          // 8nal ints (fp16 x16)
        int4*  g2h       = g1h + 2 * nal;                // 8nal ints
        float* a         = (float*)(g2h + 2 * nal);      // 16nal floats
        int*   binnedA   = (int*)g1h;                    // alias: 32nal >= E

        hipMemsetAsync(bcnt, 0, 1024 * sizeof(int), stream);

        bhist_kernel<<<512, 256, 0, stream>>>(dst, bcnt, E, K);
        bscan_kernel<<<1, KMAX, 0, stream>>>(bcnt, bstart, gcursorF, gcursorC, K, E);

        int nblk = (E + 256 * EPT - 1) / (256 * EPT);
        bin1_kernel<<<nblk, 256, 0, stream>>>(src, dst, gcursorC, binnedA, E);
        bin2_kernel<<<KC * 4, 256, 0, stream>>>(binnedA, bstart, gcursorF, binned);

        sort_kernel<<<K, 256, 0, stream>>>(bstart, binned, row_start, dinv, n, E);

        xform1_kernel<<<(n + B - 1) / B, B, 0, stream>>>(x, W1, dinv, g1h, n);

        int nb128 = (n + 127) / 128;
        agg_raw_kernel<<<nb128, 256, 0, stream>>>(row_start, binned, g1h,
                                                  (float4*)a, n);
        fin1_kernel<<<(n + 255) / 256, 256, 0, stream>>>(a, g1h, dinv, b1, W2,
                                                         g2h, n);
        agg_fin_kernel<<<nb128, 256, 0, stream>>>(row_start, binned, g2h,
                                                  dinv, b2, (float4*)out, n);
    } else {
        // fallback: proven atomic path (fp32)
        float* w   = (float*)d_ws;
        float* deg = w;                  // nal  (becomes dinv)
        float* a1  = w + nal;            // 16*nal (becomes g2)
        float* g1  = a1 + 16 * nal;      // 16*nal

        hipMemsetAsync(d_ws, 0, (nal * 17) * sizeof(float), stream);
        hipMemsetAsync(d_out, 0, (size_t)out_size * sizeof(float), stream);

        deg_kernel<<<(E + B - 1) / B, B, 0, stream>>>(dst, deg, E);
        dinv_kernel<<<(n + B - 1) / B, B, 0, stream>>>(deg, n);
        xform1_flat_kernel<<<(n + B - 1) / B, B, 0, stream>>>(x, W1, deg, g1, n);
        long long total = (long long)E * HID;
        agg_kernel<<<(int)((total + B - 1) / B), B, 0, stream>>>(src, dst, g1, a1, total);
        fin1_xform2_nolds_kernel<<<(n + B - 1) / B, B, 0, stream>>>(a1, g1, deg, b1, W2, n);
        agg_kernel<<<(int)((total + B - 1) / B), B, 0, stream>>>(src, dst, a1, out, total);
        fin2_kernel<<<(n + B - 1) / B, B, 0, stream>>>(out, a1, deg, b2, n);
    }
}